// Round 1
// baseline (239.682 us; speedup 1.0000x reference)
//
#include <hip/hip_runtime.h>

typedef __bf16 bf16;
typedef float f32x4 __attribute__((ext_vector_type(4)));
typedef bf16 bf16x4 __attribute__((ext_vector_type(4)));
typedef bf16 bf16x8 __attribute__((ext_vector_type(8)));

#define MFMA16(a, b, c) __builtin_amdgcn_mfma_f32_16x16x32_bf16((a), (b), (c), 0, 0, 0)

__device__ __forceinline__ bf16x8 mkfrag(bf16x4 lo, bf16x4 hi) {
    return __builtin_shufflevector(lo, hi, 0, 1, 2, 3, 4, 5, 6, 7);
}
__device__ __forceinline__ f32x4 zero4() {
    f32x4 z; z[0] = 0.f; z[1] = 0.f; z[2] = 0.f; z[3] = 0.f; return z;
}

// MODE 0: A = f32 x [M,K]; epilogue scatters bf16 into q/k/v ws laid out [B,H,T,d]
// MODE 1: A = bf16 att [M,K]; epilogue writes f32 out[M,N] + bias
template <int MODE>
__global__ __launch_bounds__(256)
void gemm_k(const void* __restrict__ Ap, const float* __restrict__ Bw,
            const float* __restrict__ bias,
            bf16* __restrict__ qw, bf16* __restrict__ kw, bf16* __restrict__ vw,
            float* __restrict__ outp, int M, int N, int K)
{
    __shared__ bf16 As[128][68];   // [row][k], +4 pad: stride 136B, conflict-spread
    __shared__ bf16 Bs[128][68];   // [col][k] (B stored transposed: contiguous in k)

    const int tid  = threadIdx.x;
    const int lane = tid & 63;
    const int wid  = tid >> 6;
    const int g    = lane >> 4;
    const int l16  = lane & 15;
    const int wr   = wid >> 1;     // wave row (0..1)
    const int wc   = wid & 1;      // wave col (0..1)
    const int m0   = blockIdx.y << 7;
    const int n0   = blockIdx.x << 7;

    f32x4 acc[4][4];
    #pragma unroll
    for (int i = 0; i < 4; ++i)
        #pragma unroll
        for (int j = 0; j < 4; ++j)
            acc[i][j] = zero4();

    const int nk = K >> 6;
    for (int kt = 0; kt < nk; ++kt) {
        const int k0 = kt << 6;
        __syncthreads();
        // ---- stage A tile: 128 rows x 64 k ----
        #pragma unroll
        for (int it = 0; it < 8; ++it) {
            const int f4 = tid + (it << 8);        // 0..2047 groups of 4
            const int r  = f4 >> 4;
            const int c4 = (f4 & 15) << 2;
            bf16x4 bv;
            if (MODE == 0) {
                const float4 v = *(const float4*)((const float*)Ap + (size_t)(m0 + r) * K + k0 + c4);
                bv[0] = (bf16)v.x; bv[1] = (bf16)v.y; bv[2] = (bf16)v.z; bv[3] = (bf16)v.w;
            } else {
                bv = *(const bf16x4*)((const bf16*)Ap + (size_t)(m0 + r) * K + k0 + c4);
            }
            *(bf16x4*)&As[r][c4] = bv;
        }
        // ---- stage B tile (w is [K][N] row-major) transposed into Bs[n][k] ----
        #pragma unroll
        for (int it = 0; it < 8; ++it) {
            const int f4 = tid + (it << 8);
            const int kk = f4 >> 5;                // 0..63
            const int c4 = (f4 & 31) << 2;         // 0..124
            const float4 v = *(const float4*)(Bw + (size_t)(k0 + kk) * N + n0 + c4);
            Bs[c4 + 0][kk] = (bf16)v.x;
            Bs[c4 + 1][kk] = (bf16)v.y;
            Bs[c4 + 2][kk] = (bf16)v.z;
            Bs[c4 + 3][kk] = (bf16)v.w;
        }
        __syncthreads();
        // ---- 2 MFMA K-steps of 32 ----
        #pragma unroll
        for (int ks = 0; ks < 2; ++ks) {
            const int kk = (ks << 5) + (g << 2);
            bf16x8 af[4], bfr[4];
            #pragma unroll
            for (int mf = 0; mf < 4; ++mf) {
                const int r = (wr << 6) + (mf << 4) + l16;
                af[mf] = mkfrag(*(const bf16x4*)&As[r][kk], *(const bf16x4*)&As[r][kk + 16]);
            }
            #pragma unroll
            for (int nf = 0; nf < 4; ++nf) {
                const int c = (wc << 6) + (nf << 4) + l16;
                bfr[nf] = mkfrag(*(const bf16x4*)&Bs[c][kk], *(const bf16x4*)&Bs[c][kk + 16]);
            }
            #pragma unroll
            for (int mf = 0; mf < 4; ++mf)
                #pragma unroll
                for (int nf = 0; nf < 4; ++nf)
                    acc[mf][nf] = MFMA16(af[mf], bfr[nf], acc[mf][nf]);
        }
    }

    // ---- epilogue: C/D frag map col=lane&15, row=(lane>>4)*4+reg ----
    #pragma unroll
    for (int mf = 0; mf < 4; ++mf) {
        #pragma unroll
        for (int nf = 0; nf < 4; ++nf) {
            const int ng = n0 + (wc << 6) + (nf << 4) + l16;
            const float bs = bias[ng];
            #pragma unroll
            for (int j = 0; j < 4; ++j) {
                const int mg = m0 + (wr << 6) + (mf << 4) + (g << 2) + j;
                const float v = acc[mf][nf][j] + bs;
                if (MODE == 0) {
                    const int which = ng >> 10;       // 0:q 1:k 2:v
                    const int c  = ng & 1023;
                    const int hh = c >> 6, dd = c & 63;
                    const int b  = mg >> 10, t = mg & 1023;
                    bf16* dst = (which == 0) ? qw : (which == 1) ? kw : vw;
                    dst[(size_t)((b << 4) + hh) * 65536 + (t << 6) + dd] = (bf16)v;
                } else {
                    outp[(size_t)mg * N + ng] = v;
                }
            }
        }
    }
}

// Flash attention: grid (T/64, B*H), 256 threads = 4 waves x 16 q-rows.
// Q,K,V bf16 [B,H,T,64]; out att bf16 [B,T,H*64].
__global__ __launch_bounds__(256)
void attn_k(const bf16* __restrict__ Q, const bf16* __restrict__ Kp,
            const bf16* __restrict__ V, bf16* __restrict__ att)
{
    __shared__ bf16 Ks[64][68];        // K tile [kv][d]
    __shared__ bf16 VTs[64][68];       // V tile transposed [d][kv]
    __shared__ bf16 Ps[4][16][68];     // per-wave P relayout buffer [q][kv]

    const int qt = blockIdx.x;         // q-tile (0..15)
    const int bh = blockIdx.y;         // 0..63
    const int b  = bh >> 4, h = bh & 15;

    const int tid  = threadIdx.x;
    const int lane = tid & 63;
    const int wid  = tid >> 6;
    const int g    = lane >> 4;
    const int l16  = lane & 15;

    const size_t hoff = (size_t)bh << 16;   // bh * 1024 * 64
    const bf16* Qh = Q + hoff;
    const bf16* Kh = Kp + hoff;
    const bf16* Vh = V + hoff;

    // hoist Q fragments, pre-scaled by 1/sqrt(64) = 0.125 (exact in bf16)
    const int qrow = (qt << 6) + (wid << 4) + l16;
    bf16x8 qf[2];
    #pragma unroll
    for (int ks = 0; ks < 2; ++ks) {
        const int kk = (ks << 5) + (g << 2);
        bf16x4 lo = *(const bf16x4*)(Qh + ((size_t)qrow << 6) + kk);
        bf16x4 hi = *(const bf16x4*)(Qh + ((size_t)qrow << 6) + kk + 16);
        bf16x4 lo2, hi2;
        #pragma unroll
        for (int e = 0; e < 4; ++e) {
            lo2[e] = (bf16)(0.125f * (float)lo[e]);
            hi2[e] = (bf16)(0.125f * (float)hi[e]);
        }
        qf[ks] = mkfrag(lo2, hi2);
    }

    f32x4 acc_o[4];
    float m_r[4], l_r[4];
    #pragma unroll
    for (int i = 0; i < 4; ++i) { acc_o[i] = zero4(); m_r[i] = -1e30f; l_r[i] = 0.f; }

    for (int kt = 0; kt <= qt; ++kt) {
        __syncthreads();
        // ---- stage K rows and V transposed ----
        #pragma unroll
        for (int it = 0; it < 4; ++it) {
            const int idx = tid + (it << 8);       // 0..1023
            const int r  = idx >> 4;
            const int dq = (idx & 15) << 2;
            const size_t goff = ((size_t)((kt << 6) + r) << 6) + dq;
            bf16x4 kv4 = *(const bf16x4*)(Kh + goff);
            *(bf16x4*)&Ks[r][dq] = kv4;
            bf16x4 vv4 = *(const bf16x4*)(Vh + goff);
            VTs[dq + 0][r] = vv4[0];
            VTs[dq + 1][r] = vv4[1];
            VTs[dq + 2][r] = vv4[2];
            VTs[dq + 3][r] = vv4[3];
        }
        __syncthreads();

        // ---- S = (Q/8) K^T : rows = 16 q, cols = 64 kv ----
        f32x4 sacc[4];
        #pragma unroll
        for (int cb = 0; cb < 4; ++cb) sacc[cb] = zero4();
        #pragma unroll
        for (int ks = 0; ks < 2; ++ks) {
            const int kk = (ks << 5) + (g << 2);
            #pragma unroll
            for (int cb = 0; cb < 4; ++cb) {
                const int col = (cb << 4) + l16;
                bf16x8 kf = mkfrag(*(const bf16x4*)&Ks[col][kk], *(const bf16x4*)&Ks[col][kk + 16]);
                sacc[cb] = MFMA16(qf[ks], kf, sacc[cb]);
            }
        }
        // causal mask only on the diagonal tile
        if (kt == qt) {
            #pragma unroll
            for (int cb = 0; cb < 4; ++cb) {
                const int col = (cb << 4) + l16;
                #pragma unroll
                for (int j = 0; j < 4; ++j) {
                    const int row = (wid << 4) + (g << 2) + j;
                    if (col > row) sacc[cb][j] = -1e30f;
                }
            }
        }
        // ---- online softmax (stats per row = g*4+j, reduce over 16-lane group) ----
        float pmax[4];
        #pragma unroll
        for (int j = 0; j < 4; ++j) {
            float v = fmaxf(fmaxf(sacc[0][j], sacc[1][j]), fmaxf(sacc[2][j], sacc[3][j]));
            v = fmaxf(v, __shfl_xor(v, 1));
            v = fmaxf(v, __shfl_xor(v, 2));
            v = fmaxf(v, __shfl_xor(v, 4));
            v = fmaxf(v, __shfl_xor(v, 8));
            pmax[j] = v;
        }
        float sc[4], rsum[4];
        #pragma unroll
        for (int j = 0; j < 4; ++j) {
            const float mn = fmaxf(m_r[j], pmax[j]);
            sc[j]  = __expf(m_r[j] - mn);
            m_r[j] = mn;
            rsum[j] = 0.f;
        }
        #pragma unroll
        for (int cb = 0; cb < 4; ++cb) {
            #pragma unroll
            for (int j = 0; j < 4; ++j) {
                const float p = __expf(sacc[cb][j] - m_r[j]);
                sacc[cb][j] = p;
                rsum[j] += p;
            }
        }
        #pragma unroll
        for (int j = 0; j < 4; ++j) {
            float v = rsum[j];
            v += __shfl_xor(v, 1);
            v += __shfl_xor(v, 2);
            v += __shfl_xor(v, 4);
            v += __shfl_xor(v, 8);
            l_r[j] = l_r[j] * sc[j] + v;
            acc_o[0][j] *= sc[j];
            acc_o[1][j] *= sc[j];
            acc_o[2][j] *= sc[j];
            acc_o[3][j] *= sc[j];
        }
        // ---- P -> per-wave LDS (bf16), re-read as A-fragments (in-order LDS within wave) ----
        #pragma unroll
        for (int cb = 0; cb < 4; ++cb)
            #pragma unroll
            for (int j = 0; j < 4; ++j)
                Ps[wid][(g << 2) + j][(cb << 4) + l16] = (bf16)sacc[cb][j];
        // ---- O += P V ----
        #pragma unroll
        for (int ks = 0; ks < 2; ++ks) {
            const int kk = (ks << 5) + (g << 2);
            bf16x8 pf = mkfrag(*(const bf16x4*)&Ps[wid][l16][kk], *(const bf16x4*)&Ps[wid][l16][kk + 16]);
            #pragma unroll
            for (int cb = 0; cb < 4; ++cb) {
                const int col = (cb << 4) + l16;
                bf16x8 vf = mkfrag(*(const bf16x4*)&VTs[col][kk], *(const bf16x4*)&VTs[col][kk + 16]);
                acc_o[cb] = MFMA16(pf, vf, acc_o[cb]);
            }
        }
    }

    // ---- epilogue: att[b, t, h*64+d] ----
    float inv_l[4];
    #pragma unroll
    for (int j = 0; j < 4; ++j) inv_l[j] = 1.f / l_r[j];
    #pragma unroll
    for (int cb = 0; cb < 4; ++cb) {
        #pragma unroll
        for (int j = 0; j < 4; ++j) {
            const int t = (qt << 6) + (wid << 4) + (g << 2) + j;
            const int d = (cb << 4) + l16;
            att[(((size_t)b << 10) + t) * 1024 + (h << 6) + d] = (bf16)(acc_o[cb][j] * inv_l[j]);
        }
    }
}

extern "C" void kernel_launch(void* const* d_in, const int* in_sizes, int n_in,
                              void* d_out, int out_size, void* d_ws, size_t ws_size,
                              hipStream_t stream)
{
    const float* x      = (const float*)d_in[0];
    const float* w_attn = (const float*)d_in[1];
    const float* b_attn = (const float*)d_in[2];
    const float* w_proj = (const float*)d_in[3];
    const float* b_proj = (const float*)d_in[4];
    float* out = (float*)d_out;

    const size_t NH = (size_t)4 * 16 * 1024 * 64;   // 4,194,304 elems per tensor
    bf16* qw = (bf16*)d_ws;
    bf16* kw = qw + NH;
    bf16* vw = kw + NH;
    bf16* aw = vw + NH;                              // att out [4096][1024] bf16

    // QKV GEMM: [4096,1024] x [1024,3072] -> scatter q/k/v [B,H,T,d]
    gemm_k<0><<<dim3(24, 32), 256, 0, stream>>>(x, w_attn, b_attn, qw, kw, vw,
                                                nullptr, 4096, 3072, 1024);
    // causal flash attention per (b,h,q-tile)
    attn_k<<<dim3(16, 64), 256, 0, stream>>>(qw, kw, vw, aw);
    // proj GEMM: [4096,1024] x [1024,1024] + bias -> f32 out
    gemm_k<1><<<dim3(8, 32), 256, 0, stream>>>(aw, w_proj, b_proj, nullptr, nullptr, nullptr,
                                               out, 4096, 1024, 1024);
}

// Round 2
// 177.204 us; speedup vs baseline: 1.3526x; 1.3526x over previous
//
#include <hip/hip_runtime.h>

typedef __bf16 bf16;
typedef float f32x4 __attribute__((ext_vector_type(4)));
typedef bf16 bf16x4 __attribute__((ext_vector_type(4)));
typedef bf16 bf16x8 __attribute__((ext_vector_type(8)));

#define MFMA16(a, b, c) __builtin_amdgcn_mfma_f32_16x16x32_bf16((a), (b), (c), 0, 0, 0)

__device__ __forceinline__ f32x4 zero4() {
    f32x4 z; z[0] = 0.f; z[1] = 0.f; z[2] = 0.f; z[3] = 0.f; return z;
}
__device__ __forceinline__ bf16x8 mkfrag(bf16x4 lo, bf16x4 hi) {
    return __builtin_shufflevector(lo, hi, 0, 1, 2, 3, 4, 5, 6, 7);
}
// async global -> LDS, 16B per lane. LDS dest must be wave-uniform base; HW adds lane*16.
__device__ __forceinline__ void gl_lds16(const bf16* g, bf16* l) {
    __builtin_amdgcn_global_load_lds(
        (const __attribute__((address_space(1))) void*)g,
        (__attribute__((address_space(3))) void*)l, 16, 0, 0);
}

// ---------------- prep: f32 -> bf16 elementwise ----------------
__global__ __launch_bounds__(256) void conv_k(const float* __restrict__ src,
                                              bf16* __restrict__ dst, int n)
{
    const int i = (blockIdx.x * 256 + threadIdx.x) * 8;
    if (i >= n) return;
    const float4 a = *(const float4*)(src + i);
    const float4 b = *(const float4*)(src + i + 4);
    bf16x8 o;
    o[0] = (bf16)a.x; o[1] = (bf16)a.y; o[2] = (bf16)a.z; o[3] = (bf16)a.w;
    o[4] = (bf16)b.x; o[5] = (bf16)b.y; o[6] = (bf16)b.z; o[7] = (bf16)b.w;
    *(bf16x8*)(dst + i) = o;
}

// ---------------- prep: transpose+convert w [K][N] f32 -> wT [N][K] bf16 ----------------
__global__ __launch_bounds__(256) void transp_k(const float* __restrict__ src,
                                                bf16* __restrict__ dst, int K, int N)
{
    __shared__ bf16 Ls[64][72];
    const int tid = threadIdx.x;
    const int k0 = blockIdx.y << 6;
    const int n0 = blockIdx.x << 6;
    #pragma unroll
    for (int it = 0; it < 4; ++it) {
        const int lin = (it << 10) + (tid << 2);
        const int r = lin >> 6, c = lin & 63;
        const float4 v = *(const float4*)(src + (size_t)(k0 + r) * N + n0 + c);
        bf16x4 o; o[0] = (bf16)v.x; o[1] = (bf16)v.y; o[2] = (bf16)v.z; o[3] = (bf16)v.w;
        *(bf16x4*)&Ls[r][c] = o;
    }
    __syncthreads();
    #pragma unroll
    for (int it = 0; it < 2; ++it) {
        const int lin = (it << 11) + (tid << 3);
        const int nn = lin >> 6, kk = lin & 63;
        bf16x8 o;
        #pragma unroll
        for (int j = 0; j < 8; ++j) o[j] = Ls[kk + j][nn];
        *(bf16x8*)(dst + (size_t)(n0 + nn) * K + k0 + kk) = o;
    }
}

// ---------------- bf16 GEMM, B^T input, m97 structure ----------------
// A [M][K] bf16, Bt [N][K] bf16. MODE 0: bf16 out + bias. MODE 1: f32 out + bias.
// BN = 128 (waves 2x2, 64x64 each) or 64 (waves 4x1, 32x64 each). BM=128, BK=64.
template <int MODE, int BN>
__global__ __launch_bounds__(256)
void gemm_bt(const bf16* __restrict__ A, const bf16* __restrict__ Bt,
             const float* __restrict__ bias, bf16* __restrict__ outb,
             float* __restrict__ outf, int M, int N, int K)
{
    __shared__ bf16 As[128 * 64];
    __shared__ bf16 Bs[BN * 64];

    constexpr int MF = (BN == 128) ? 4 : 2;     // 16-row frags per wave (M)
    constexpr int NF = 4;                       // 16-col frags per wave (N)

    const int tid  = threadIdx.x;
    const int lane = tid & 63;
    const int wid  = tid >> 6;
    const int l16  = lane & 15;
    const int g    = lane >> 4;
    const int g8   = g << 3;
    const int wrb  = (BN == 128) ? ((wid >> 1) << 6) : (wid << 5);  // wave row base
    const int wcb  = (BN == 128) ? ((wid & 1) << 6) : 0;            // wave col base
    const int m0   = blockIdx.y << 7;
    const int n0   = blockIdx.x * BN;

    const int arow = lane >> 3;          // staging: row-in-8 block
    const int acol = (lane & 7) << 3;    // staging: 8-elem col chunk

    f32x4 acc[MF][NF];
    #pragma unroll
    for (int i = 0; i < MF; ++i)
        #pragma unroll
        for (int j = 0; j < NF; ++j) acc[i][j] = zero4();

    const int nk = K >> 6;
    for (int kt = 0; kt < nk; ++kt) {
        const int k0 = kt << 6;
        __syncthreads();
        // stage A tile: 128 rows x 64 k, 16 wave-insts (4/wave)
        #pragma unroll
        for (int i = 0; i < 4; ++i) {
            const int row = (wid << 5) + (i << 3);
            gl_lds16(A + (size_t)(m0 + row + arow) * K + k0 + acol, As + row * 64);
        }
        // stage B tile: BN rows x 64 k
        #pragma unroll
        for (int i = 0; i < BN / 32; ++i) {
            const int row = wid * (BN / 4) + (i << 3);
            gl_lds16(Bt + (size_t)(n0 + row + arow) * K + k0 + acol, Bs + row * 64);
        }
        __syncthreads();   // drains vmcnt(0): staged data visible
        #pragma unroll
        for (int ks = 0; ks < 2; ++ks) {
            const int kk = (ks << 5) + g8;
            bf16x8 af[MF], bfr[NF];
            #pragma unroll
            for (int mf = 0; mf < MF; ++mf)
                af[mf] = *(const bf16x8*)&As[(wrb + (mf << 4) + l16) * 64 + kk];
            #pragma unroll
            for (int nf = 0; nf < NF; ++nf)
                bfr[nf] = *(const bf16x8*)&Bs[(wcb + (nf << 4) + l16) * 64 + kk];
            #pragma unroll
            for (int mf = 0; mf < MF; ++mf)
                #pragma unroll
                for (int nf = 0; nf < NF; ++nf)
                    acc[mf][nf] = MFMA16(af[mf], bfr[nf], acc[mf][nf]);
        }
    }

    // epilogue: C/D map col=lane&15, row=(lane>>4)*4+reg
    #pragma unroll
    for (int mf = 0; mf < MF; ++mf) {
        #pragma unroll
        for (int nf = 0; nf < NF; ++nf) {
            const int ng = n0 + wcb + (nf << 4) + l16;
            const float bs = bias[ng];
            #pragma unroll
            for (int j = 0; j < 4; ++j) {
                const int mg = m0 + wrb + (mf << 4) + (g << 2) + j;
                const float v = acc[mf][nf][j] + bs;
                if (MODE == 0) outb[(size_t)mg * N + ng] = (bf16)v;
                else           outf[(size_t)mg * N + ng] = v;
            }
        }
    }
}

// ---------------- flash attention ----------------
// qkv [4096][3072] bf16 (Q|K|V each 1024 cols; head h at cols h*64).
// out att [4096][1024] bf16 (= [b,t,h*64+d]).
__global__ __launch_bounds__(256)
void attn_k(const bf16* __restrict__ qkv, bf16* __restrict__ att)
{
    __shared__ bf16 Ks[64][72];
    __shared__ bf16 VTs[64][72];
    __shared__ bf16 Ps[4][16][72];

    const int qt = blockIdx.x;          // q tile (0..15)
    const int bh = blockIdx.y;          // 0..63
    const int b  = bh >> 4, h = bh & 15;

    const int tid  = threadIdx.x;
    const int lane = tid & 63;
    const int wid  = tid >> 6;
    const int g    = lane >> 4;
    const int l16  = lane & 15;
    const int g8   = g << 3;

    const size_t rb = (size_t)b << 10;  // base row of this batch
    const int hc = h << 6;

    // hoist Q fragments (contiguous k-map), pre-scaled by 0.125
    const int qrow = (qt << 6) + (wid << 4) + l16;
    const bf16* qp = qkv + (rb + qrow) * 3072 + hc;
    bf16x8 qf[2];
    #pragma unroll
    for (int ks = 0; ks < 2; ++ks) {
        bf16x8 v = *(const bf16x8*)(qp + (ks << 5) + g8);
        #pragma unroll
        for (int e = 0; e < 8; ++e) v[e] = (bf16)(0.125f * (float)v[e]);
        qf[ks] = v;
    }

    f32x4 acc_o[4];
    float m_r[4], l_r[4];
    #pragma unroll
    for (int i = 0; i < 4; ++i) { acc_o[i] = zero4(); m_r[i] = -1e30f; l_r[i] = 0.f; }

    for (int kt = 0; kt <= qt; ++kt) {
        __syncthreads();
        // stage K rows and V transposed (16B global loads)
        #pragma unroll
        for (int it = 0; it < 2; ++it) {
            const int idx = (it << 8) + tid;        // 0..511
            const int r = idx >> 3, c8 = (idx & 7) << 3;
            const bf16* kp = qkv + (rb + (kt << 6) + r) * 3072 + 1024 + hc + c8;
            *(bf16x8*)&Ks[r][c8] = *(const bf16x8*)kp;
            const bf16x8 vv = *(const bf16x8*)(kp + 1024);
            #pragma unroll
            for (int j = 0; j < 8; ++j) VTs[c8 + j][r] = vv[j];
        }
        __syncthreads();

        // S = (Q/8) K^T : 16 q rows x 64 kv cols per wave
        f32x4 sacc[4];
        #pragma unroll
        for (int cb = 0; cb < 4; ++cb) sacc[cb] = zero4();
        #pragma unroll
        for (int ks = 0; ks < 2; ++ks) {
            const int kk = (ks << 5) + g8;
            #pragma unroll
            for (int cb = 0; cb < 4; ++cb) {
                bf16x8 kf = *(const bf16x8*)&Ks[(cb << 4) + l16][kk];
                sacc[cb] = MFMA16(qf[ks], kf, sacc[cb]);
            }
        }
        if (kt == qt) {   // causal mask on diagonal tile
            #pragma unroll
            for (int cb = 0; cb < 4; ++cb) {
                const int col = (cb << 4) + l16;
                #pragma unroll
                for (int j = 0; j < 4; ++j) {
                    const int row = (wid << 4) + (g << 2) + j;
                    if (col > row) sacc[cb][j] = -1e30f;
                }
            }
        }
        // online softmax: stats per row (g*4+j), reduce over 16-lane group
        float pmax[4];
        #pragma unroll
        for (int j = 0; j < 4; ++j) {
            float v = fmaxf(fmaxf(sacc[0][j], sacc[1][j]), fmaxf(sacc[2][j], sacc[3][j]));
            v = fmaxf(v, __shfl_xor(v, 1));
            v = fmaxf(v, __shfl_xor(v, 2));
            v = fmaxf(v, __shfl_xor(v, 4));
            v = fmaxf(v, __shfl_xor(v, 8));
            pmax[j] = v;
        }
        float sc[4], rsum[4];
        #pragma unroll
        for (int j = 0; j < 4; ++j) {
            const float mn = fmaxf(m_r[j], pmax[j]);
            sc[j] = __expf(m_r[j] - mn);
            m_r[j] = mn;
            rsum[j] = 0.f;
        }
        #pragma unroll
        for (int cb = 0; cb < 4; ++cb)
            #pragma unroll
            for (int j = 0; j < 4; ++j) {
                const float p = __expf(sacc[cb][j] - m_r[j]);
                sacc[cb][j] = p;
                rsum[j] += p;
            }
        #pragma unroll
        for (int j = 0; j < 4; ++j) {
            float v = rsum[j];
            v += __shfl_xor(v, 1);
            v += __shfl_xor(v, 2);
            v += __shfl_xor(v, 4);
            v += __shfl_xor(v, 8);
            l_r[j] = l_r[j] * sc[j] + v;
            acc_o[0][j] *= sc[j];
            acc_o[1][j] *= sc[j];
            acc_o[2][j] *= sc[j];
            acc_o[3][j] *= sc[j];
        }
        // P -> per-wave LDS, re-read as A-frags (contiguous k-map)
        #pragma unroll
        for (int cb = 0; cb < 4; ++cb)
            #pragma unroll
            for (int j = 0; j < 4; ++j)
                Ps[wid][(g << 2) + j][(cb << 4) + l16] = (bf16)sacc[cb][j];
        // O += P V
        #pragma unroll
        for (int ks = 0; ks < 2; ++ks) {
            const int kk = (ks << 5) + g8;
            bf16x8 pf = *(const bf16x8*)&Ps[wid][l16][kk];
            #pragma unroll
            for (int cb = 0; cb < 4; ++cb) {
                bf16x8 vf = *(const bf16x8*)&VTs[(cb << 4) + l16][kk];
                acc_o[cb] = MFMA16(pf, vf, acc_o[cb]);
            }
        }
    }

    float inv_l[4];
    #pragma unroll
    for (int j = 0; j < 4; ++j) inv_l[j] = 1.f / l_r[j];
    #pragma unroll
    for (int cb = 0; cb < 4; ++cb)
        #pragma unroll
        for (int j = 0; j < 4; ++j) {
            const int t = (qt << 6) + (wid << 4) + (g << 2) + j;
            const int d = (cb << 4) + l16;
            att[(rb + t) * 1024 + hc + d] = (bf16)(acc_o[cb][j] * inv_l[j]);
        }
}

extern "C" void kernel_launch(void* const* d_in, const int* in_sizes, int n_in,
                              void* d_out, int out_size, void* d_ws, size_t ws_size,
                              hipStream_t stream)
{
    const float* x      = (const float*)d_in[0];
    const float* w_attn = (const float*)d_in[1];
    const float* b_attn = (const float*)d_in[2];
    const float* w_proj = (const float*)d_in[3];
    const float* b_proj = (const float*)d_in[4];
    float* out = (float*)d_out;

    // workspace layout (bf16 elems)
    bf16* xb   = (bf16*)d_ws;                       // [4096][1024]      8.4 MB
    bf16* wT   = xb  + (size_t)4096 * 1024;         // [3072][1024]      6.3 MB
    bf16* wpT  = wT  + (size_t)3072 * 1024;         // [1024][1024]      2.1 MB
    bf16* qkvb = wpT + (size_t)1024 * 1024;         // [4096][3072]     25.2 MB
    bf16* aw   = qkvb + (size_t)4096 * 3072;        // [4096][1024]      8.4 MB

    conv_k<<<2048, 256, 0, stream>>>(x, xb, 4096 * 1024);
    transp_k<<<dim3(48, 16), 256, 0, stream>>>(w_attn, wT, 1024, 3072);
    transp_k<<<dim3(16, 16), 256, 0, stream>>>(w_proj, wpT, 1024, 1024);

    gemm_bt<0, 128><<<dim3(24, 32), 256, 0, stream>>>(xb, wT, b_attn, qkvb, nullptr,
                                                      4096, 3072, 1024);
    attn_k<<<dim3(16, 64), 256, 0, stream>>>(qkvb, aw);
    gemm_bt<1, 64><<<dim3(16, 32), 256, 0, stream>>>(aw, wpT, b_proj, nullptr, out,
                                                     4096, 1024, 1024);
}

// Round 3
// 169.989 us; speedup vs baseline: 1.4100x; 1.0424x over previous
//
#include <hip/hip_runtime.h>

typedef __bf16 bf16;
typedef float f32x4 __attribute__((ext_vector_type(4)));
typedef bf16 bf16x4 __attribute__((ext_vector_type(4)));
typedef bf16 bf16x8 __attribute__((ext_vector_type(8)));

#define MFMA16(a, b, c) __builtin_amdgcn_mfma_f32_16x16x32_bf16((a), (b), (c), 0, 0, 0)

__device__ __forceinline__ f32x4 zero4() {
    f32x4 z; z[0] = 0.f; z[1] = 0.f; z[2] = 0.f; z[3] = 0.f; return z;
}
// async global -> LDS, 16B per lane. LDS dest must be wave-uniform base; HW adds lane*16.
__device__ __forceinline__ void gl_lds16(const bf16* g, bf16* l) {
    __builtin_amdgcn_global_load_lds(
        (const __attribute__((address_space(1))) void*)g,
        (__attribute__((address_space(3))) void*)l, 16, 0, 0);
}

// ---------------- prep: f32 -> bf16 elementwise ----------------
__global__ __launch_bounds__(256) void conv_k(const float* __restrict__ src,
                                              bf16* __restrict__ dst, int n)
{
    const int i = (blockIdx.x * 256 + threadIdx.x) * 8;
    if (i >= n) return;
    const float4 a = *(const float4*)(src + i);
    const float4 b = *(const float4*)(src + i + 4);
    bf16x8 o;
    o[0] = (bf16)a.x; o[1] = (bf16)a.y; o[2] = (bf16)a.z; o[3] = (bf16)a.w;
    o[4] = (bf16)b.x; o[5] = (bf16)b.y; o[6] = (bf16)b.z; o[7] = (bf16)b.w;
    *(bf16x8*)(dst + i) = o;
}

// ---------------- prep: transpose+convert w [K][N] f32 -> wT [N][K] bf16 ----------------
__global__ __launch_bounds__(256) void transp_k(const float* __restrict__ src,
                                                bf16* __restrict__ dst, int K, int N)
{
    __shared__ bf16 Ls[64][72];
    const int tid = threadIdx.x;
    const int k0 = blockIdx.y << 6;
    const int n0 = blockIdx.x << 6;
    #pragma unroll
    for (int it = 0; it < 4; ++it) {
        const int lin = (it << 10) + (tid << 2);
        const int r = lin >> 6, c = lin & 63;
        const float4 v = *(const float4*)(src + (size_t)(k0 + r) * N + n0 + c);
        bf16x4 o; o[0] = (bf16)v.x; o[1] = (bf16)v.y; o[2] = (bf16)v.z; o[3] = (bf16)v.w;
        *(bf16x4*)&Ls[r][c] = o;
    }
    __syncthreads();
    #pragma unroll
    for (int it = 0; it < 2; ++it) {
        const int lin = (it << 11) + (tid << 3);
        const int nn = lin >> 6, kk = lin & 63;
        bf16x8 o;
        #pragma unroll
        for (int j = 0; j < 8; ++j) o[j] = Ls[kk + j][nn];
        *(bf16x8*)(dst + (size_t)(n0 + nn) * K + k0 + kk) = o;
    }
}

// ---------------- bf16 GEMM, B^T input, m97 structure ----------------
// A [M][K] bf16, Bt [N][K] bf16.
// MODE 0: scatter q/k packed [bh][t][d] + v transposed [bh][d][t] (bf16, +bias)
// MODE 1: f32 out[M][N] + bias
template <int MODE, int BN>
__global__ __launch_bounds__(256)
void gemm_bt(const bf16* __restrict__ A, const bf16* __restrict__ Bt,
             const float* __restrict__ bias,
             bf16* __restrict__ qw, bf16* __restrict__ kw, bf16* __restrict__ vw,
             float* __restrict__ outf, int M, int N, int K)
{
    __shared__ bf16 As[128 * 64];
    __shared__ bf16 Bs[BN * 64];

    constexpr int MF = (BN == 128) ? 4 : 2;
    constexpr int NF = 4;

    const int tid  = threadIdx.x;
    const int lane = tid & 63;
    const int wid  = tid >> 6;
    const int l16  = lane & 15;
    const int g    = lane >> 4;
    const int g8   = g << 3;
    const int wrb  = (BN == 128) ? ((wid >> 1) << 6) : (wid << 5);
    const int wcb  = (BN == 128) ? ((wid & 1) << 6) : 0;
    const int m0   = blockIdx.y << 7;
    const int n0   = blockIdx.x * BN;

    const int arow = lane >> 3;
    const int acol = (lane & 7) << 3;

    f32x4 acc[MF][NF];
    #pragma unroll
    for (int i = 0; i < MF; ++i)
        #pragma unroll
        for (int j = 0; j < NF; ++j) acc[i][j] = zero4();

    const int nk = K >> 6;
    for (int kt = 0; kt < nk; ++kt) {
        const int k0 = kt << 6;
        __syncthreads();
        #pragma unroll
        for (int i = 0; i < 4; ++i) {
            const int row = (wid << 5) + (i << 3);
            gl_lds16(A + (size_t)(m0 + row + arow) * K + k0 + acol, As + row * 64);
        }
        #pragma unroll
        for (int i = 0; i < BN / 32; ++i) {
            const int row = wid * (BN / 4) + (i << 3);
            gl_lds16(Bt + (size_t)(n0 + row + arow) * K + k0 + acol, Bs + row * 64);
        }
        __syncthreads();
        #pragma unroll
        for (int ks = 0; ks < 2; ++ks) {
            const int kk = (ks << 5) + g8;
            bf16x8 af[MF], bfr[NF];
            #pragma unroll
            for (int mf = 0; mf < MF; ++mf)
                af[mf] = *(const bf16x8*)&As[(wrb + (mf << 4) + l16) * 64 + kk];
            #pragma unroll
            for (int nf = 0; nf < NF; ++nf)
                bfr[nf] = *(const bf16x8*)&Bs[(wcb + (nf << 4) + l16) * 64 + kk];
            #pragma unroll
            for (int mf = 0; mf < MF; ++mf)
                #pragma unroll
                for (int nf = 0; nf < NF; ++nf)
                    acc[mf][nf] = MFMA16(af[mf], bfr[nf], acc[mf][nf]);
        }
    }

    // epilogue: C/D map col=lane&15, row=(lane>>4)*4+reg
    #pragma unroll
    for (int mf = 0; mf < MF; ++mf) {
        #pragma unroll
        for (int nf = 0; nf < NF; ++nf) {
            const int ng = n0 + wcb + (nf << 4) + l16;
            const float bs = bias[ng];
            #pragma unroll
            for (int j = 0; j < 4; ++j) {
                const int mg = m0 + wrb + (mf << 4) + (g << 2) + j;
                const float v = acc[mf][nf][j] + bs;
                if (MODE == 0) {
                    const int which = ng >> 10;          // 0:q 1:k 2:v
                    const int c  = ng & 1023;
                    const int hh = c >> 6, dd = c & 63;
                    const int b  = mg >> 10, t = mg & 1023;
                    const size_t hb = (size_t)((b << 4) + hh) << 16;
                    if (which == 0)      qw[hb + (t << 6) + dd] = (bf16)v;
                    else if (which == 1) kw[hb + (t << 6) + dd] = (bf16)v;
                    else                 vw[hb + ((size_t)dd << 10) + t] = (bf16)v;  // V^T
                } else {
                    outf[(size_t)mg * N + ng] = v;
                }
            }
        }
    }
}

// ---------------- flash attention, barrier-free ----------------
// Q,K packed [bh][1024][64]; Vt [bh][64][1024]. out att [4096][1024] bf16.
// grid (16, 64) x 256 thr. Wave w of block bx owns q-tile16 {bx,31-bx,32+bx,63-bx}[w].
__global__ __launch_bounds__(256, 4)
void attn_k(const bf16* __restrict__ Qp, const bf16* __restrict__ Kp,
            const bf16* __restrict__ Vt, bf16* __restrict__ att)
{
    __shared__ bf16 Ps[4][2][16][72];   // per-wave, double-buffered P relayout

    const int bx = blockIdx.x;          // 0..15
    const int bh = blockIdx.y;          // 0..63
    const int b  = bh >> 4, h = bh & 15;

    const int tid  = threadIdx.x;
    const int lane = tid & 63;
    const int wid  = tid >> 6;
    const int g    = lane >> 4;
    const int l16  = lane & 15;
    const int g8   = g << 3;

    int qt16;
    if      (wid == 0) qt16 = bx;
    else if (wid == 1) qt16 = 31 - bx;
    else if (wid == 2) qt16 = 32 + bx;
    else               qt16 = 63 - bx;
    const int q0 = qt16 << 4;

    const size_t hb = (size_t)bh << 16;
    const bf16* Qh = Qp + hb;
    const bf16* Kh = Kp + hb;
    const bf16* Vh = Vt + hb;

    // hoist Q fragments (rows = l16), pre-scaled by 1/8
    bf16x8 qf[2];
    #pragma unroll
    for (int ks = 0; ks < 2; ++ks) {
        bf16x8 v = *(const bf16x8*)(Qh + ((size_t)(q0 + l16) << 6) + (ks << 5) + g8);
        #pragma unroll
        for (int e = 0; e < 8; ++e) v[e] = (bf16)(0.125f * (float)v[e]);
        qf[ks] = v;
    }

    f32x4 acc_o[4];
    float m_r[4], l_r[4];
    #pragma unroll
    for (int i = 0; i < 4; ++i) { acc_o[i] = zero4(); m_r[i] = -1e30f; l_r[i] = 0.f; }

    const int nkt = qt16 >> 2;          // last kv tile index
    for (int kt = 0; kt <= nkt; ++kt) {
        const int kv0 = kt << 6;
        // ---- S = (Q/8) K^T ----
        f32x4 sacc[4];
        #pragma unroll
        for (int cb = 0; cb < 4; ++cb) sacc[cb] = zero4();
        #pragma unroll
        for (int ks = 0; ks < 2; ++ks) {
            bf16x8 kf[4];
            #pragma unroll
            for (int cb = 0; cb < 4; ++cb)
                kf[cb] = *(const bf16x8*)(Kh + ((size_t)(kv0 + (cb << 4) + l16) << 6) + (ks << 5) + g8);
            #pragma unroll
            for (int cb = 0; cb < 4; ++cb)
                sacc[cb] = MFMA16(qf[ks], kf[cb], sacc[cb]);
        }
        // ---- prefetch V^T fragments (independent of softmax) ----
        bf16x8 vf[2][4];
        #pragma unroll
        for (int ks = 0; ks < 2; ++ks)
            #pragma unroll
            for (int cb = 0; cb < 4; ++cb)
                vf[ks][cb] = *(const bf16x8*)(Vh + (((size_t)((cb << 4) + l16)) << 10) + kv0 + (ks << 5) + g8);
        // ---- causal mask (only final tile is partial) ----
        if (kt == nkt) {
            #pragma unroll
            for (int cb = 0; cb < 4; ++cb) {
                const int col = kv0 + (cb << 4) + l16;
                #pragma unroll
                for (int j = 0; j < 4; ++j) {
                    const int row = q0 + (g << 2) + j;
                    if (col > row) sacc[cb][j] = -1e30f;
                }
            }
        }
        // ---- online softmax (row stats over 16-lane group) ----
        float pmax[4];
        #pragma unroll
        for (int j = 0; j < 4; ++j) {
            float v = fmaxf(fmaxf(sacc[0][j], sacc[1][j]), fmaxf(sacc[2][j], sacc[3][j]));
            v = fmaxf(v, __shfl_xor(v, 1));
            v = fmaxf(v, __shfl_xor(v, 2));
            v = fmaxf(v, __shfl_xor(v, 4));
            v = fmaxf(v, __shfl_xor(v, 8));
            pmax[j] = v;
        }
        float sc[4], rsum[4];
        #pragma unroll
        for (int j = 0; j < 4; ++j) {
            const float mn = fmaxf(m_r[j], pmax[j]);
            sc[j] = __expf(m_r[j] - mn);
            m_r[j] = mn;
            rsum[j] = 0.f;
        }
        #pragma unroll
        for (int cb = 0; cb < 4; ++cb)
            #pragma unroll
            for (int j = 0; j < 4; ++j) {
                const float p = __expf(sacc[cb][j] - m_r[j]);
                sacc[cb][j] = p;
                rsum[j] += p;
            }
        #pragma unroll
        for (int j = 0; j < 4; ++j) {
            float v = rsum[j];
            v += __shfl_xor(v, 1);
            v += __shfl_xor(v, 2);
            v += __shfl_xor(v, 4);
            v += __shfl_xor(v, 8);
            l_r[j] = l_r[j] * sc[j] + v;
            acc_o[0][j] *= sc[j];
            acc_o[1][j] *= sc[j];
            acc_o[2][j] *= sc[j];
            acc_o[3][j] *= sc[j];
        }
        // ---- P relayout through per-wave LDS (double-buffered) ----
        const int pb = kt & 1;
        #pragma unroll
        for (int cb = 0; cb < 4; ++cb)
            #pragma unroll
            for (int j = 0; j < 4; ++j)
                Ps[wid][pb][(g << 2) + j][(cb << 4) + l16] = (bf16)sacc[cb][j];
        // ---- O += P V ----
        #pragma unroll
        for (int ks = 0; ks < 2; ++ks) {
            bf16x8 pf = *(const bf16x8*)&Ps[wid][pb][l16][(ks << 5) + g8];
            #pragma unroll
            for (int cb = 0; cb < 4; ++cb)
                acc_o[cb] = MFMA16(pf, vf[ks][cb], acc_o[cb]);
        }
    }

    // ---- epilogue: att[b*1024+t][h*64+d] ----
    float inv_l[4];
    #pragma unroll
    for (int j = 0; j < 4; ++j) inv_l[j] = 1.f / l_r[j];
    #pragma unroll
    for (int cb = 0; cb < 4; ++cb)
        #pragma unroll
        for (int j = 0; j < 4; ++j) {
            const int t = q0 + (g << 2) + j;
            const int d = (cb << 4) + l16;
            att[(((size_t)b << 10) + t) * 1024 + (h << 6) + d] = (bf16)(acc_o[cb][j] * inv_l[j]);
        }
}

extern "C" void kernel_launch(void* const* d_in, const int* in_sizes, int n_in,
                              void* d_out, int out_size, void* d_ws, size_t ws_size,
                              hipStream_t stream)
{
    const float* x      = (const float*)d_in[0];
    const float* w_attn = (const float*)d_in[1];
    const float* b_attn = (const float*)d_in[2];
    const float* w_proj = (const float*)d_in[3];
    const float* b_proj = (const float*)d_in[4];
    float* out = (float*)d_out;

    // workspace layout (bf16 elems), total 24M elems = 48MB
    bf16* xb  = (bf16*)d_ws;                        // [4096][1024]
    bf16* wT  = xb  + (size_t)4096 * 1024;          // [3072][1024]
    bf16* wpT = wT  + (size_t)3072 * 1024;          // [1024][1024]
    bf16* qw  = wpT + (size_t)1024 * 1024;          // [64 bh][1024 t][64 d]
    bf16* kw  = qw  + (size_t)64 * 1024 * 64;       // [64 bh][1024 t][64 d]
    bf16* vw  = kw  + (size_t)64 * 1024 * 64;       // [64 bh][64 d][1024 t]
    bf16* aw  = vw  + (size_t)64 * 1024 * 64;       // [4096][1024]

    conv_k<<<2048, 256, 0, stream>>>(x, xb, 4096 * 1024);
    transp_k<<<dim3(48, 16), 256, 0, stream>>>(w_attn, wT, 1024, 3072);
    transp_k<<<dim3(16, 16), 256, 0, stream>>>(w_proj, wpT, 1024, 1024);

    gemm_bt<0, 128><<<dim3(24, 32), 256, 0, stream>>>(xb, wT, b_attn, qw, kw, vw,
                                                      nullptr, 4096, 3072, 1024);
    attn_k<<<dim3(16, 64), 256, 0, stream>>>(qw, kw, vw, aw);
    gemm_bt<1, 64><<<dim3(16, 32), 256, 0, stream>>>(aw, wpT, b_proj, nullptr, nullptr, nullptr,
                                                     out, 4096, 1024, 1024);
}

// Round 5
// 109.765 us; speedup vs baseline: 2.1836x; 1.5487x over previous
//
#include <hip/hip_runtime.h>

typedef __bf16 bf16;
typedef float f32x4 __attribute__((ext_vector_type(4)));
typedef bf16 bf16x4 __attribute__((ext_vector_type(4)));
typedef bf16 bf16x8 __attribute__((ext_vector_type(8)));

#define MFMA16(a, b, c) __builtin_amdgcn_mfma_f32_16x16x32_bf16((a), (b), (c), 0, 0, 0)

__device__ __forceinline__ f32x4 zero4() {
    f32x4 z; z[0] = 0.f; z[1] = 0.f; z[2] = 0.f; z[3] = 0.f; return z;
}
// async global -> LDS, 16B/lane. LDS dest = wave-uniform base + lane*16.
__device__ __forceinline__ void gl_lds16(const bf16* g, bf16* l) {
    __builtin_amdgcn_global_load_lds(
        (const __attribute__((address_space(1))) void*)g,
        (__attribute__((address_space(3))) void*)l, 16, 0, 0);
}

// ---------------- prep: f32 -> bf16 elementwise ----------------
__global__ __launch_bounds__(256) void conv_k(const float* __restrict__ src,
                                              bf16* __restrict__ dst, int n)
{
    const int i = (blockIdx.x * 256 + threadIdx.x) * 8;
    if (i >= n) return;
    const float4 a = *(const float4*)(src + i);
    const float4 b = *(const float4*)(src + i + 4);
    bf16x8 o;
    o[0] = (bf16)a.x; o[1] = (bf16)a.y; o[2] = (bf16)a.z; o[3] = (bf16)a.w;
    o[4] = (bf16)b.x; o[5] = (bf16)b.y; o[6] = (bf16)b.z; o[7] = (bf16)b.w;
    *(bf16x8*)(dst + i) = o;
}

// ---------------- prep: transpose+convert w [K][N] f32 -> wT [N][K] bf16 ----------------
__global__ __launch_bounds__(256) void transp_k(const float* __restrict__ src,
                                                bf16* __restrict__ dst, int K, int N)
{
    __shared__ bf16 Ls[64][72];
    const int tid = threadIdx.x;
    const int k0 = blockIdx.y << 6;
    const int n0 = blockIdx.x << 6;
    #pragma unroll
    for (int it = 0; it < 4; ++it) {
        const int lin = (it << 10) + (tid << 2);
        const int r = lin >> 6, c = lin & 63;
        const float4 v = *(const float4*)(src + (size_t)(k0 + r) * N + n0 + c);
        bf16x4 o; o[0] = (bf16)v.x; o[1] = (bf16)v.y; o[2] = (bf16)v.z; o[3] = (bf16)v.w;
        *(bf16x4*)&Ls[r][c] = o;
    }
    __syncthreads();
    #pragma unroll
    for (int it = 0; it < 2; ++it) {
        const int lin = (it << 11) + (tid << 3);
        const int nn = lin >> 6, kk = lin & 63;
        bf16x8 o;
        #pragma unroll
        for (int j = 0; j < 8; ++j) o[j] = Ls[kk + j][nn];
        *(bf16x8*)(dst + (size_t)(n0 + nn) * K + k0 + kk) = o;
    }
}

// ---------------- bf16 GEMM, B^T input, 2-phase dbuf pipeline, BK=32 ----------------
// A [M][K] bf16, Bt [N][K] bf16.
// MODE 0 (BN=128): scatter q/k packed [bh][t][d] + v transposed [bh][d][t] via LDS-pack
// MODE 1 (BN=64):  f32 out[M][N] + bias, direct stores
template <int MODE, int BN>
__global__ __launch_bounds__(256)
void gemm_bt(const bf16* __restrict__ A, const bf16* __restrict__ Bt,
             const float* __restrict__ bias,
             bf16* __restrict__ qw, bf16* __restrict__ kw, bf16* __restrict__ vw,
             float* __restrict__ outf, int M, int N, int K)
{
    constexpr int BK = 32;
    constexpr int MF = (BN == 128) ? 4 : 2;
    constexpr int NF = 4;
    constexpr int AE = 128 * BK;
    constexpr int BE = BN * BK;

    __shared__ __align__(16) bf16 smem[2 * AE + 2 * BE];
    bf16* const As0 = smem;
    bf16* const As1 = smem + AE;
    bf16* const Bs0 = smem + 2 * AE;
    bf16* const Bs1 = smem + 2 * AE + BE;

    const int tid  = threadIdx.x;
    const int lane = tid & 63;
    const int wid  = tid >> 6;
    const int l16  = lane & 15;
    const int g    = lane >> 4;
    const int wrb  = (BN == 128) ? ((wid >> 1) << 6) : (wid << 5);
    const int wcb  = (BN == 128) ? ((wid & 1) << 6) : 0;
    const int m0   = blockIdx.y << 7;
    const int n0   = blockIdx.x * BN;

    // staging: 16 rows x 64B per instr; source chunk XOR-preswizzled by (row>>1)&3
    const int srow = lane >> 2;
    const int schk = lane & 3;
    const int rA0 = (wid << 5) + srow;
    const int rA1 = rA0 + 16;
    const int rB0 = wid * (BN / 4) + srow;
    const int rB1 = rB0 + 16;
    const bf16* pa0 = A  + (size_t)(m0 + rA0) * K + ((schk ^ ((rA0 >> 1) & 3)) << 3);
    const bf16* pa1 = A  + (size_t)(m0 + rA1) * K + ((schk ^ ((rA1 >> 1) & 3)) << 3);
    const bf16* pb0 = Bt + (size_t)(n0 + rB0) * K + ((schk ^ ((rB0 >> 1) & 3)) << 3);
    const bf16* pb1 = Bt + (size_t)(n0 + rB1) * K + ((schk ^ ((rB1 >> 1) & 3)) << 3);
    const int dA0 = (wid << 5) * BK, dA1 = dA0 + 16 * BK;
    const int dB0 = (wid * (BN / 4)) * BK, dB1 = dB0 + 16 * BK;

    // fragment read offsets (elems), swizzle-matched
    int offA[MF], offB[NF];
    #pragma unroll
    for (int mf = 0; mf < MF; ++mf) {
        const int r = wrb + (mf << 4) + l16;
        offA[mf] = r * BK + ((g ^ ((r >> 1) & 3)) << 3);
    }
    #pragma unroll
    for (int nf = 0; nf < NF; ++nf) {
        const int r = wcb + (nf << 4) + l16;
        offB[nf] = r * BK + ((g ^ ((r >> 1) & 3)) << 3);
    }

    f32x4 acc[MF][NF];
    #pragma unroll
    for (int i = 0; i < MF; ++i)
        #pragma unroll
        for (int j = 0; j < NF; ++j) acc[i][j] = zero4();

    const int nk = K >> 5;
    // prologue: stage tile 0 into buf0
    gl_lds16(pa0, As0 + dA0); gl_lds16(pa1, As0 + dA1);
    gl_lds16(pb0, Bs0 + dB0);
    if (BN == 128) gl_lds16(pb1, Bs0 + dB1);
    pa0 += BK; pa1 += BK; pb0 += BK; pb1 += BK;
    __syncthreads();

    for (int kt = 0; kt < nk; ++kt) {
        const bool odd = kt & 1;
        if (kt + 1 < nk) {                       // prefetch next tile into other buffer
            bf16* an = odd ? As0 : As1;
            bf16* bn = odd ? Bs0 : Bs1;
            gl_lds16(pa0, an + dA0); gl_lds16(pa1, an + dA1);
            gl_lds16(pb0, bn + dB0);
            if (BN == 128) gl_lds16(pb1, bn + dB1);
            pa0 += BK; pa1 += BK; pb0 += BK; pb1 += BK;
        }
        const bf16* ac = odd ? As1 : As0;
        const bf16* bc = odd ? Bs1 : Bs0;
        bf16x8 af[MF], bfr[NF];
        #pragma unroll
        for (int mf = 0; mf < MF; ++mf) af[mf] = *(const bf16x8*)&ac[offA[mf]];
        #pragma unroll
        for (int nf = 0; nf < NF; ++nf) bfr[nf] = *(const bf16x8*)&bc[offB[nf]];
        #pragma unroll
        for (int mf = 0; mf < MF; ++mf)
            #pragma unroll
            for (int nf = 0; nf < NF; ++nf)
                acc[mf][nf] = MFMA16(af[mf], bfr[nf], acc[mf][nf]);
        __syncthreads();                         // drains vmcnt(0): prefetched tile ready
    }

    if (MODE == 0) {
        // ---- LDS-pack epilogue: 128x128 bf16 tile reusing smem (exactly 32KB) ----
        bf16* const Es = smem;
        const int bq  = m0 >> 10;
        const int tb  = m0 & 1023;               // time index within batch (FIX)
        const int hh0 = (n0 & 1023) >> 6;
        const bool isV = (n0 >= 2048);
        if (isV) {
            #pragma unroll
            for (int mf = 0; mf < MF; ++mf)
                #pragma unroll
                for (int nf = 0; nf < NF; ++nf) {
                    const int nn = wcb + (nf << 4) + l16;
                    const float bs = bias[n0 + nn];
                    bf16x4 p;
                    #pragma unroll
                    for (int j = 0; j < 4; ++j) p[j] = (bf16)(acc[mf][nf][j] + bs);
                    *(bf16x4*)&Es[nn * 128 + wrb + (mf << 4) + (g << 2)] = p;  // transposed
                }
        } else {
            #pragma unroll
            for (int mf = 0; mf < MF; ++mf)
                #pragma unroll
                for (int nf = 0; nf < NF; ++nf) {
                    const int nn = wcb + (nf << 4) + l16;
                    const float bs = bias[n0 + nn];
                    #pragma unroll
                    for (int j = 0; j < 4; ++j) {
                        const int mm = wrb + (mf << 4) + (g << 2) + j;
                        Es[mm * 128 + nn] = (bf16)(acc[mf][nf][j] + bs);
                    }
                }
        }
        __syncthreads();
        #pragma unroll
        for (int it = 0; it < 8; ++it) {
            const int idx = (it << 8) + tid;
            const int row = idx >> 4, ch = idx & 15;
            const bf16x8 v = *(const bf16x8*)&Es[row * 128 + (ch << 3)];
            if (isV) {
                const int dd = row & 63, hh = hh0 + (row >> 6);
                *(bf16x8*)(vw + ((size_t)((bq << 4) + hh) << 16) + ((size_t)dd << 10)
                           + tb + (ch << 3)) = v;
            } else {
                const int t = tb + row;
                const int cc = ch << 3;
                const int hh = hh0 + (cc >> 6);
                bf16* const dst = (n0 < 1024) ? qw : kw;
                *(bf16x8*)(dst + ((size_t)((bq << 4) + hh) << 16) + ((size_t)t << 6)
                           + (cc & 63)) = v;
            }
        }
    } else {
        #pragma unroll
        for (int mf = 0; mf < MF; ++mf)
            #pragma unroll
            for (int nf = 0; nf < NF; ++nf) {
                const int ng = n0 + wcb + (nf << 4) + l16;
                const float bs = bias[ng];
                #pragma unroll
                for (int j = 0; j < 4; ++j) {
                    const int mg = m0 + wrb + (mf << 4) + (g << 2) + j;
                    outf[(size_t)mg * N + ng] = acc[mf][nf][j] + bs;
                }
            }
    }
}

// ---------------- flash attention: 4 waves x 16 q-rows, LDS K/V^T dbuf 2-phase ----------------
// Q,K [bh][1024][64]; Vt [bh][64][1024]; out att [4096][1024] bf16.
// grid (8, 64); block bx does q-blocks {bx, 15-bx} of 64 rows -> 17 kv-tiles/block uniform.
__global__ __launch_bounds__(256)
void attn_k(const bf16* __restrict__ Qp, const bf16* __restrict__ Kp,
            const bf16* __restrict__ Vt, bf16* __restrict__ att)
{
    __shared__ __align__(16) bf16 Kl0[64 * 64], Kl1[64 * 64];
    __shared__ __align__(16) bf16 Vl0[64 * 64], Vl1[64 * 64];
    __shared__ __align__(16) bf16 Ps[4][16 * 72];

    const int bx = blockIdx.x;          // 0..7
    const int bh = blockIdx.y;          // 0..63
    const int b  = bh >> 4, h = bh & 15;

    const int tid  = threadIdx.x;
    const int lane = tid & 63;
    const int wid  = tid >> 6;
    const int g    = lane >> 4;
    const int l16  = lane & 15;
    const int g8   = g << 3;

    const size_t hb = (size_t)bh << 16;
    const bf16* Qh = Qp + hb;
    const bf16* Kh = Kp + hb;
    const bf16* Vh = Vt + hb;

    // staging: 8 rows x 128B per instr; source chunk XOR-preswizzled by row&7
    const int srow = lane >> 3;                    // 0..7
    const int sswz = ((lane & 7) ^ srow) << 3;     // elems
    const int kr0  = (wid << 4) + srow;
    const int kr1  = kr0 + 8;
    const int dst0 = (wid << 4) << 6;
    const int dst1 = ((wid << 4) + 8) << 6;

    // fragment read offsets (elems), swizzle-matched; shared by K and V^T tiles
    int offKV[2][4];
    #pragma unroll
    for (int ks = 0; ks < 2; ++ks)
        #pragma unroll
        for (int cb = 0; cb < 4; ++cb) {
            const int r = (cb << 4) + l16;
            offKV[ks][cb] = (r << 6) + (((((ks << 2) + g)) ^ (r & 7)) << 3);
        }

    bf16* const Pw = &Ps[wid][0];

    for (int pass = 0; pass < 2; ++pass) {
        const int qb = pass ? (15 - bx) : bx;
        const int q0 = qb << 6;

        // hoist Q fragments for this wave's 16 rows, pre-scaled by 1/8
        const bf16* qp = Qh + ((size_t)(q0 + (wid << 4) + l16) << 6) + g8;
        bf16x8 qf0 = *(const bf16x8*)qp;
        bf16x8 qf1 = *(const bf16x8*)(qp + 32);
        #pragma unroll
        for (int e = 0; e < 8; ++e) {
            qf0[e] = (bf16)(0.125f * (float)qf0[e]);
            qf1[e] = (bf16)(0.125f * (float)qf1[e]);
        }

        f32x4 acc_o[4];
        float m_r[4], l_r[4];
        #pragma unroll
        for (int i = 0; i < 4; ++i) { acc_o[i] = zero4(); m_r[i] = -1e30f; l_r[i] = 0.f; }

        // prologue: stage kv tile 0 into buf0
        gl_lds16(Kh + ((size_t)kr0 << 6) + sswz, Kl0 + dst0);
        gl_lds16(Kh + ((size_t)kr1 << 6) + sswz, Kl0 + dst1);
        gl_lds16(Vh + ((size_t)kr0 << 10) + sswz, Vl0 + dst0);
        gl_lds16(Vh + ((size_t)kr1 << 10) + sswz, Vl0 + dst1);
        __syncthreads();

        for (int kt = 0; kt <= qb; ++kt) {
            const bool odd = kt & 1;
            if (kt < qb) {                       // prefetch next kv tile
                const int kv1 = (kt + 1) << 6;
                bf16* Kn = odd ? Kl0 : Kl1;
                bf16* Vn = odd ? Vl0 : Vl1;
                gl_lds16(Kh + ((size_t)(kv1 + kr0) << 6) + sswz, Kn + dst0);
                gl_lds16(Kh + ((size_t)(kv1 + kr1) << 6) + sswz, Kn + dst1);
                gl_lds16(Vh + ((size_t)kr0 << 10) + kv1 + sswz, Vn + dst0);
                gl_lds16(Vh + ((size_t)kr1 << 10) + kv1 + sswz, Vn + dst1);
            }
            const bf16* Kc = odd ? Kl1 : Kl0;
            const bf16* Vc = odd ? Vl1 : Vl0;

            // ---- S = (Q/8) K^T ----
            f32x4 sacc[4];
            #pragma unroll
            for (int cb = 0; cb < 4; ++cb) sacc[cb] = zero4();
            #pragma unroll
            for (int cb = 0; cb < 4; ++cb) {
                const bf16x8 kf = *(const bf16x8*)&Kc[offKV[0][cb]];
                sacc[cb] = MFMA16(qf0, kf, sacc[cb]);
            }
            #pragma unroll
            for (int cb = 0; cb < 4; ++cb) {
                const bf16x8 kf = *(const bf16x8*)&Kc[offKV[1][cb]];
                sacc[cb] = MFMA16(qf1, kf, sacc[cb]);
            }
            // ---- causal mask on diagonal tile ----
            if (kt == qb) {
                #pragma unroll
                for (int cb = 0; cb < 4; ++cb) {
                    const int col = (cb << 4) + l16;
                    #pragma unroll
                    for (int j = 0; j < 4; ++j) {
                        const int row = (wid << 4) + (g << 2) + j;
                        if (col > row) sacc[cb][j] = -1e30f;
                    }
                }
            }
            // ---- online softmax (row stats over 16-lane group) ----
            float pmax[4];
            #pragma unroll
            for (int j = 0; j < 4; ++j) {
                float v = fmaxf(fmaxf(sacc[0][j], sacc[1][j]), fmaxf(sacc[2][j], sacc[3][j]));
                v = fmaxf(v, __shfl_xor(v, 1));
                v = fmaxf(v, __shfl_xor(v, 2));
                v = fmaxf(v, __shfl_xor(v, 4));
                v = fmaxf(v, __shfl_xor(v, 8));
                pmax[j] = v;
            }
            float sc[4], rsum[4];
            #pragma unroll
            for (int j = 0; j < 4; ++j) {
                const float mn = fmaxf(m_r[j], pmax[j]);
                sc[j] = __expf(m_r[j] - mn);
                m_r[j] = mn;
                rsum[j] = 0.f;
            }
            #pragma unroll
            for (int cb = 0; cb < 4; ++cb)
                #pragma unroll
                for (int j = 0; j < 4; ++j) {
                    const float p = __expf(sacc[cb][j] - m_r[j]);
                    sacc[cb][j] = p;
                    rsum[j] += p;
                }
            #pragma unroll
            for (int j = 0; j < 4; ++j) {
                float v = rsum[j];
                v += __shfl_xor(v, 1);
                v += __shfl_xor(v, 2);
                v += __shfl_xor(v, 4);
                v += __shfl_xor(v, 8);
                l_r[j] = l_r[j] * sc[j] + v;
                acc_o[0][j] *= sc[j];
                acc_o[1][j] *= sc[j];
                acc_o[2][j] *= sc[j];
                acc_o[3][j] *= sc[j];
            }
            // ---- P relayout via per-wave LDS ----
            #pragma unroll
            for (int cb = 0; cb < 4; ++cb)
                #pragma unroll
                for (int j = 0; j < 4; ++j)
                    Pw[((g << 2) + j) * 72 + (cb << 4) + l16] = (bf16)sacc[cb][j];
            // ---- O += P V ----
            #pragma unroll
            for (int ks = 0; ks < 2; ++ks) {
                const bf16x8 pf = *(const bf16x8*)&Pw[l16 * 72 + (ks << 5) + g8];
                #pragma unroll
                for (int cb = 0; cb < 4; ++cb) {
                    const bf16x8 vf = *(const bf16x8*)&Vc[offKV[ks][cb]];
                    acc_o[cb] = MFMA16(pf, vf, acc_o[cb]);
                }
            }
            __syncthreads();
        }

        // ---- epilogue: att[b*1024+t][h*64+d] ----
        float inv_l[4];
        #pragma unroll
        for (int j = 0; j < 4; ++j) inv_l[j] = 1.f / l_r[j];
        #pragma unroll
        for (int cb = 0; cb < 4; ++cb)
            #pragma unroll
            for (int j = 0; j < 4; ++j) {
                const int t = q0 + (wid << 4) + (g << 2) + j;
                const int d = (cb << 4) + l16;
                att[(((size_t)b << 10) + t) * 1024 + (h << 6) + d]
                    = (bf16)(acc_o[cb][j] * inv_l[j]);
            }
    }
}

extern "C" void kernel_launch(void* const* d_in, const int* in_sizes, int n_in,
                              void* d_out, int out_size, void* d_ws, size_t ws_size,
                              hipStream_t stream)
{
    const float* x      = (const float*)d_in[0];
    const float* w_attn = (const float*)d_in[1];
    const float* b_attn = (const float*)d_in[2];
    const float* w_proj = (const float*)d_in[3];
    const float* b_proj = (const float*)d_in[4];
    float* out = (float*)d_out;

    // workspace layout (bf16 elems)
    bf16* xb  = (bf16*)d_ws;                        // [4096][1024]
    bf16* wT  = xb  + (size_t)4096 * 1024;          // [3072][1024]
    bf16* wpT = wT  + (size_t)3072 * 1024;          // [1024][1024]
    bf16* qw  = wpT + (size_t)1024 * 1024;          // [64 bh][1024 t][64 d]
    bf16* kw  = qw  + (size_t)64 * 1024 * 64;       // [64 bh][1024 t][64 d]
    bf16* vw  = kw  + (size_t)64 * 1024 * 64;       // [64 bh][64 d][1024 t]
    bf16* aw  = vw  + (size_t)64 * 1024 * 64;       // [4096][1024]

    conv_k<<<2048, 256, 0, stream>>>(x, xb, 4096 * 1024);
    transp_k<<<dim3(48, 16), 256, 0, stream>>>(w_attn, wT, 1024, 3072);
    transp_k<<<dim3(16, 16), 256, 0, stream>>>(w_proj, wpT, 1024, 1024);

    gemm_bt<0, 128><<<dim3(24, 32), 256, 0, stream>>>(xb, wT, b_attn, qw, kw, vw,
                                                      nullptr, 4096, 3072, 1024);
    attn_k<<<dim3(8, 64), 256, 0, stream>>>(qw, kw, vw, aw);
    gemm_bt<1, 64><<<dim3(16, 32), 256, 0, stream>>>(aw, wpT, b_proj, nullptr, nullptr, nullptr,
                                                     out, 4096, 1024, 1024);
}